// Round 10
// baseline (161.997 us; speedup 1.0000x reference)
//
#include <hip/hip_runtime.h>
#include <stdint.h>

// TypedLinear: out[i] = W[types[i]] @ x[i] + b[types[i]]
// N=65536, IN=OUT=256, T=8, fp32 in/out. bf16-MFMA grouped-GEMM.
// Read-side scatter moved out of the GEMM: bucket pass gathers x into bucket
// order as bf16, pre-XOR-swizzled (xg). FIX vs r9: bucket starts PADDED to a
// multiple of 64 rows so every tile base is 0 mod 8 and the gather-side
// swizzle key (g&7) equals the read-side key (row&7). GEMM A-stage is 8 async
// global_load_lds(16B)/wave from contiguous xg; compute/epilogue = r2's
// verified structure; single barrier. Only scatter left: the out-row write.
// Dispatches: memset(64B) + prep_hist + bucket_gather + gemm.

#define NROWS 65536
#define NTYPES 8
#define KDIM 256
#define ODIM 256
#define BM 64
#define MAX_TILES (NROWS / BM + NTYPES - 1)   // 1031 worst case

typedef __attribute__((ext_vector_type(8))) short short8;
typedef __attribute__((ext_vector_type(4))) float f32x4;

__device__ __forceinline__ unsigned short f2bf(float f) {
    // round-to-nearest-even fp32 -> bf16
    unsigned int u = __float_as_uint(f);
    u += 0x7fffu + ((u >> 16) & 1u);
    return (unsigned short)(u >> 16);
}

// ---------------- k1: W pack + global type histogram ----------------
// blocks [0,256): pack W fp32 -> bf16 in MFMA-fragment order (coalesced map):
//   Wp[((t*16+f)*8+q)*512 + l*8 + e] = bf16(W[t][f*16+(l&15)][q*32+(l>>4)*8+e])
// blocks [256,512): global histogram of types into cnt[8].
// cnt[0..16) pre-zeroed by one 64B hipMemsetAsync.
__global__ void prep_hist_kernel(const float* __restrict__ W,
                                 unsigned short* __restrict__ Wp,
                                 const int* __restrict__ types,
                                 int* __restrict__ cnt) {
    const int b = blockIdx.x;
    if (b < 256) {
        const int gid = b * 256 + threadIdx.x;      // 0..65535
        const int R   = gid >> 5;                   // W row: t*256 + r
        const int c32 = gid & 31;                   // 8-float chunk of the row
        const int t  = R >> 8;
        const int r  = R & 255;
        const int f  = r >> 4;
        const int rr = r & 15;
        const int q  = c32 >> 2;
        const int l  = (c32 & 3) * 16 + rr;
        const float* src = W + (size_t)R * KDIM + c32 * 8;
        const float4 v0 = *(const float4*)src;
        const float4 v1 = *(const float4*)(src + 4);
        ushort4 p0, p1;
        p0.x = f2bf(v0.x); p0.y = f2bf(v0.y); p0.z = f2bf(v0.z); p0.w = f2bf(v0.w);
        p1.x = f2bf(v1.x); p1.y = f2bf(v1.y); p1.z = f2bf(v1.z); p1.w = f2bf(v1.w);
        ushort4* dst = (ushort4*)(Wp + (size_t)(((t * 16 + f) * 8 + q) * 512 + l * 8));
        dst[0] = p0; dst[1] = p1;
    } else {
        __shared__ int h[NTYPES];
        const int i = (b - 256) * 256 + threadIdx.x;
        if (threadIdx.x < NTYPES) h[threadIdx.x] = 0;
        __syncthreads();
        atomicAdd(&h[types[i]], 1);
        __syncthreads();
        if (threadIdx.x < NTYPES) atomicAdd(&cnt[threadIdx.x], h[threadIdx.x]);
    }
}

// ---------------- k2: bucket + gather x -> xg (bf16, bucket order, swizzled) --
// 1024 blocks x 256 threads; 64 rows/block. Threads 0..63 classify; the 4
// waves then copy 16 rows each: one float4/lane (full 1KB fp32 row per instr),
// convert, 8B store into xg with the As XOR swizzle pre-applied:
//   xg[g*512 + ((c ^ (g&7))*16) + (l&1)*8],  c = l>>1.
// Bucket starts ps[t] are PADDED to multiples of 64 rows (so g&7 == local row&7
// inside every 64-row tile). Also writes idx[g] = original row.
__global__ __launch_bounds__(256)
void bucket_gather_kernel(const float* __restrict__ x,
                          const int* __restrict__ types,
                          int* __restrict__ cnt,        // [0..8) hist, [8..16) cursors
                          int* __restrict__ idx,        // padded bucket order
                          char* __restrict__ xgB) {
    __shared__ int h[NTYPES];
    __shared__ int b2[NTYPES];
    __shared__ int ps[NTYPES];
    __shared__ int dst_s[64];

    const int tid = threadIdx.x;
    const int i0 = blockIdx.x * 64;

    if (tid < NTYPES) h[tid] = 0;
    __syncthreads();

    int myt = 0, myr = 0;
    if (tid < 64) {
        myt = types[i0 + tid];
        myr = atomicAdd(&h[myt], 1);
    }
    __syncthreads();
    if (tid < NTYPES) b2[tid] = atomicAdd(&cnt[NTYPES + tid], h[tid]);
    if (tid == 0) {
        int acc = 0;
        #pragma unroll
        for (int t = 0; t < NTYPES; ++t) {
            ps[t] = acc;
            acc += ((cnt[t] + 63) >> 6) << 6;      // PADDED start, mult of 64
        }
    }
    __syncthreads();
    if (tid < 64) {
        const int g = ps[myt] + b2[myt] + myr;
        dst_s[tid] = g;
        idx[g] = i0 + tid;
    }
    __syncthreads();

    const int wave = tid >> 6;
    const int lane = tid & 63;
    const int c = lane >> 1;                 // 16B chunk 0..31
    const int bo = (lane & 1) * 8;           // byte within chunk
    #pragma unroll 4
    for (int k = 0; k < 16; ++k) {
        const int rr = wave * 16 + k;
        const int g = dst_s[rr];
        const float4 v = *(const float4*)(x + (size_t)(i0 + rr) * KDIM + lane * 4);
        ushort4 p;
        p.x = f2bf(v.x); p.y = f2bf(v.y); p.z = f2bf(v.z); p.w = f2bf(v.w);
        *(ushort4*)(xgB + (size_t)g * 512 + ((c ^ (g & 7)) * 16) + bo) = p;
    }
}

// ---------------- k3: grouped GEMM ----------------
// grid (MAX_TILES): flat m-tile -> (type, m0, gbase = ps[t]+m0, 0 mod 64).
// 256 threads = 4 waves; wave owns 64 output cols. As: [64 rows][512B] bf16
// (32 KB); swizzle already applied in xg so the A-stage is 8 linear
// global_load_lds(16B)/wave. B frags from packed Wp (L2-resident). One barrier.
__global__ __launch_bounds__(256, 4)
void gemm_kernel(const float* __restrict__ bias,
                 const unsigned short* __restrict__ Wp,
                 const int* __restrict__ cnt,
                 const int* __restrict__ idx,
                 const char* __restrict__ xgB,
                 float* __restrict__ out) {
    // ---- flat tile id -> (type t, local m0, count, padded global base gbase)
    const int bid = blockIdx.x;
    int t = -1, m0 = 0, count = 0, accum = 0, rowacc = 0, gbase = 0;
    #pragma unroll
    for (int i = 0; i < NTYPES; ++i) {
        const int c = cnt[i];
        const int ntile = (c + BM - 1) / BM;
        if (t < 0 && bid < accum + ntile) {
            t = i; m0 = (bid - accum) * BM; count = c; gbase = rowacc + m0;
        }
        accum += ntile;
        rowacc += ntile * BM;                 // padded: matches ps[t]
    }
    if (t < 0) return;

    __shared__ unsigned short As[BM * KDIM];    // 32 KB, swizzled content
    __shared__ int idx_s[BM];
    char* AsB = (char*)As;

    const int tid = threadIdx.x;
    const int wave = tid >> 6;
    const int lane = tid & 63;
    const int lr = lane & 15;
    const int lq = lane >> 4;

    // ---- idx for the epilogue (clamped tail), issued before the barrier
    const int rowlim = count - m0;              // >= 1
    if (tid < BM)
        idx_s[tid] = idx[gbase + (tid < rowlim ? tid : rowlim - 1)];

    // ---- stage A: 8 async global_load_lds(16B) per wave from contiguous xg.
    // dst = wave-uniform base + lane*16 (HW); rows are 512B: lanes 0..31 fill
    // row R0, lanes 32..63 fill R0+1. Source is per-lane.
    #pragma unroll
    for (int it = 0; it < 8; ++it) {
        const int dbyte = wave * 8192 + it * 1024;          // LDS byte base
        const int R0 = wave * 16 + it * 2;                  // first row of pair
        const char* src = xgB + (size_t)(gbase + R0 + (lane >> 5)) * 512
                              + (size_t)(lane & 31) * 16;
        __builtin_amdgcn_global_load_lds(
            (const __attribute__((address_space(1))) void*)src,
            (__attribute__((address_space(3))) void*)(AsB + dbyte),
            16, 0, 0);
    }

    // ---- bias (per-wave cols), hoisted
    float bv[4];
    #pragma unroll
    for (int j = 0; j < 4; ++j)
        bv[j] = bias[t * ODIM + wave * 64 + j * 16 + lr];

    __syncthreads();    // drains vmcnt (gload_lds) + lgkm (idx_s)

    const unsigned short* Wpt = Wp + (size_t)t * 16 * 8 * 512;   // type base

    f32x4 acc[4][4] = {};

    // ---- compute: 8 k32-chunks x 16 MFMAs; B frags streamed from L2.
    #pragma unroll
    for (int q = 0; q < 8; ++q) {
        short8 bf[4], af[4];
        #pragma unroll
        for (int j = 0; j < 4; ++j)
            bf[j] = *(const short8*)(Wpt + ((size_t)((wave * 4 + j) * 8 + q)) * 512
                                         + lane * 8);
        #pragma unroll
        for (int i = 0; i < 4; ++i) {
            const int row = i * 16 + lr;
            af[i] = *(const short8*)(AsB + row * 512
                                         + (((q << 2) + lq) ^ (row & 7)) * 16);
        }
        #pragma unroll
        for (int i = 0; i < 4; ++i)
            #pragma unroll
            for (int j = 0; j < 4; ++j)
                acc[i][j] = __builtin_amdgcn_mfma_f32_16x16x32_bf16(
                    af[i], bf[j], acc[i][j], 0, 0, 0);
    }

    // ---- epilogue (r2 verified): D col = lane&15, row = (lane>>4)*4 + reg
    #pragma unroll
    for (int i = 0; i < 4; ++i) {
        #pragma unroll
        for (int r = 0; r < 4; ++r) {
            const int lm = i * 16 + lq * 4 + r;
            if (lm < rowlim) {
                const size_t orow = (size_t)idx_s[lm] * ODIM;
                #pragma unroll
                for (int j = 0; j < 4; ++j)
                    out[orow + wave * 64 + j * 16 + lr] = acc[i][j][r] + bv[j];
            }
        }
    }
}

extern "C" void kernel_launch(void* const* d_in, const int* in_sizes, int n_in,
                              void* d_out, int out_size, void* d_ws, size_t ws_size,
                              hipStream_t stream) {
    const float* x     = (const float*)d_in[0];
    const int*   types = (const int*)d_in[1];
    const float* W     = (const float*)d_in[2];
    const float* b     = (const float*)d_in[3];
    float* out = (float*)d_out;

    // ws layout:
    //   [0, 64)            cnt[8] hist + cnt[8..16) bucket cursors
    //   [4096, +264KB)     idx (padded bucket order, <=66048 ints)
    //   [274432, +1MB)     Wp packed bf16 W
    //   [1572864, +33.8MB) xg gathered bf16 x, padded bucket order, swizzled
    char* ws = (char*)d_ws;
    int* cnt = (int*)ws;
    int* idx = (int*)(ws + 4096);
    unsigned short* Wp = (unsigned short*)(ws + 274432);
    char* xgB = ws + 1572864;

    hipMemsetAsync(cnt, 0, 64, stream);
    prep_hist_kernel<<<512, 256, 0, stream>>>(W, Wp, types, cnt);
    bucket_gather_kernel<<<NROWS / 64, 256, 0, stream>>>(x, types, cnt, idx, xgB);
    gemm_kernel<<<MAX_TILES, 256, 0, stream>>>(b, Wp, cnt, idx, xgB, out);
}